// Round 3
// baseline (481.897 us; speedup 1.0000x reference)
//
#include <hip/hip_runtime.h>
#include <hip/hip_bf16.h>

using bf16 = __hip_bfloat16;
typedef __attribute__((ext_vector_type(8))) short short8;
typedef __attribute__((ext_vector_type(4))) float f32x4;

constexpr int NLAYER = 2;
constexpr int NB = 2;
constexpr int NS = 1024;
constexpr int ND = 512;
constexpr int NH = 32;
constexpr int NF = 2048;
constexpr int NC = 1000;
constexpr float EPS_LN = 1e-5f;

__device__ inline unsigned short f2bfu(float x) {
    union { bf16 h; unsigned short u; } c;
    c.h = __float2bfloat16(x);
    return c.u;
}

#define GLOAD16(gp, lp) __builtin_amdgcn_global_load_lds( \
    (const __attribute__((address_space(1))) void*)(gp),  \
    (__attribute__((address_space(3))) void*)(lp), 16, 0, 0)

// ---------------------------------------------------------------------------
// bf16 MFMA GEMM, C = A[MxK] * B^T[NxK] (+bias) (+ReLU | scores-epilogue)
// BM x BN tile, 4 waves (2x2), BK=32, mfma_f32_16x16x32_bf16.
// ---------------------------------------------------------------------------
template<int BM, int BN, bool OUTBF, bool RELU, bool SCORES>
__global__ __launch_bounds__(256) void mfma_gemm(
    const bf16* __restrict__ A, const bf16* __restrict__ B,
    const float* __restrict__ bias, void* __restrict__ Cout,
    const float* __restrict__ table,
    int K, int lda, int ldb, int ldc,
    long sA, long sB, long sC, float alpha)
{
    const int bz = blockIdx.z;
    A += (long)bz * sA;
    B += (long)bz * sB;
    const int bm = blockIdx.y * BM, bn = blockIdx.x * BN;
    __shared__ bf16 As[BM * 32], Bs[BN * 32];
    const int tid = threadIdx.x, lane = tid & 63, wv = tid >> 6;
    const int wr = (wv >> 1) * (BM / 2), wc = (wv & 1) * (BN / 2);
    constexpr int FM = BM / 32, FN = BN / 32;
    f32x4 acc[FM][FN] = {};
    const int r_a = tid >> 2;           // staging row (sweep adds 64)
    const int ko = (tid & 3) * 8;       // staging k offset (elems)
    const short8* Asv = (const short8*)As;
    const short8* Bsv = (const short8*)Bs;

    for (int k0 = 0; k0 < K; k0 += 32) {
        #pragma unroll
        for (int c = 0; c < BM / 64; ++c)
            GLOAD16(A + (long)(bm + r_a + c * 64) * lda + k0 + ko,
                    As + c * 2048 + wv * 512);
        #pragma unroll
        for (int c = 0; c < BN / 64; ++c)
            GLOAD16(B + (long)(bn + r_a + c * 64) * ldb + k0 + ko,
                    Bs + c * 2048 + wv * 512);
        __syncthreads();
        short8 af[FM], bfr[FN];
        #pragma unroll
        for (int m = 0; m < FM; ++m)
            af[m] = Asv[(wr + m * 16 + (lane & 15)) * 4 + (lane >> 4)];
        #pragma unroll
        for (int n = 0; n < FN; ++n)
            bfr[n] = Bsv[(wc + n * 16 + (lane & 15)) * 4 + (lane >> 4)];
        #pragma unroll
        for (int m = 0; m < FM; ++m)
            #pragma unroll
            for (int n = 0; n < FN; ++n)
                acc[m][n] = __builtin_amdgcn_mfma_f32_16x16x32_bf16(
                    af[m], bfr[n], acc[m][n], 0, 0, 0);
        __syncthreads();
    }

    const int er = (lane >> 4) * 4, ec = lane & 15;
    #pragma unroll
    for (int m = 0; m < FM; ++m) {
        #pragma unroll
        for (int n = 0; n < FN; ++n) {
            const int row0 = bm + wr + m * 16 + er;
            const int col  = bn + wc + n * 16 + ec;
            const float bv = bias ? bias[col] : 0.f;
            #pragma unroll
            for (int e = 0; e < 4; ++e) {
                const int row = row0 + e;
                float v = acc[m][n][e];
                if (SCORES) {
                    int di = (col >> 5) - (row >> 5) + 31;
                    int dj = (col & 31) - (row & 31) + 31;
                    v = v * alpha + table[di * 63 + dj];
                } else {
                    v += bv;
                    if (RELU) v = fmaxf(v, 0.f);
                }
                if (OUTBF)
                    ((bf16*)Cout)[bz * sC + (long)row * ldc + col] = __float2bfloat16(v);
                else
                    ((float*)Cout)[bz * sC + (long)row * ldc + col] = v;
            }
        }
    }
}

// ---------------------------------------------------------------------------
// Transpose + f32->bf16 convert: dst[C][R] = (bf16) src[R][C], batched over z
// ---------------------------------------------------------------------------
__global__ __launch_bounds__(256) void tconv_f32_kernel(
    const float* __restrict__ src, bf16* __restrict__ dst,
    int R, int C, long sS, long sD)
{
    src += (long)blockIdx.z * sS;
    dst += (long)blockIdx.z * sD;
    __shared__ float t[32][33];
    const int c0 = blockIdx.x * 32, r0 = blockIdx.y * 32;
    const int lx = threadIdx.x & 31, ly = threadIdx.x >> 5;
    for (int rr = ly; rr < 32; rr += 8)
        t[rr][lx] = src[(long)(r0 + rr) * C + c0 + lx];
    __syncthreads();
    for (int cc = ly; cc < 32; cc += 8)
        dst[(long)(c0 + cc) * R + r0 + lx] = __float2bfloat16(t[lx][cc]);
}

// bf16 transpose with leading dims (for V^T), batched over z
__global__ __launch_bounds__(256) void tbf_kernel(
    const bf16* __restrict__ src, bf16* __restrict__ dst,
    int ldsrc, int lddst, long sS, long sD)
{
    src += (long)blockIdx.z * sS;
    dst += (long)blockIdx.z * sD;
    __shared__ bf16 t[32][33];
    const int c0 = blockIdx.x * 32, r0 = blockIdx.y * 32;
    const int lx = threadIdx.x & 31, ly = threadIdx.x >> 5;
    for (int rr = ly; rr < 32; rr += 8)
        t[rr][lx] = src[(long)(r0 + rr) * ldsrc + c0 + lx];
    __syncthreads();
    for (int cc = ly; cc < 32; cc += 8)
        dst[(long)(c0 + cc) * lddst + r0 + lx] = t[lx][cc];
}

// x_cur = x_in (f32), xb = bf16(x_in)
__global__ __launch_bounds__(256) void xcopy_kernel(
    const float* __restrict__ xin, float* __restrict__ xc, bf16* __restrict__ xb)
{
    long i = (long)blockIdx.x * 256 + threadIdx.x;
    float4 v = ((const float4*)xin)[i];
    ((float4*)xc)[i] = v;
    uint2 o;
    o.x = (unsigned)f2bfu(v.x) | ((unsigned)f2bfu(v.y) << 16);
    o.y = (unsigned)f2bfu(v.z) | ((unsigned)f2bfu(v.w) << 16);
    ((uint2*)xb)[i] = o;
}

// ---------------------------------------------------------------------------
// Pair-bias table: coords form an exact 32x32 grid -> 63x63 table per layer.
// ---------------------------------------------------------------------------
__global__ __launch_bounds__(256) void bias_table_kernel(
    const float* __restrict__ coords,
    const float* __restrict__ rot_w1, const float* __restrict__ rot_b1,
    const float* __restrict__ rot_w2, const float* __restrict__ rot_b2,
    const float* __restrict__ trans_w1, const float* __restrict__ trans_b1,
    const float* __restrict__ trans_w2, const float* __restrict__ trans_b2,
    const float* __restrict__ refl_w1, const float* __restrict__ refl_b1,
    const float* __restrict__ refl_w2, const float* __restrict__ refl_b2,
    float* __restrict__ table)
{
    int idx = blockIdx.x * 256 + threadIdx.x;
    if (idx >= 63 * 63) return;
    int da = idx / 63 - 31, db = idx % 63 - 31;
    int ai = da < 0 ? -da : 0, bi = db < 0 ? -db : 0;
    int i = ai * 32 + bi, j = (ai + da) * 32 + (bi + db);
    float2 ci = ((const float2*)coords)[i];
    float2 cj = ((const float2*)coords)[j];
    float dx = cj.x - ci.x, dy = cj.y - ci.y;
    float dist = sqrtf(dx * dx + dy * dy + 1e-8f);
    float th = atan2f(dy, dx);
    float sn = sinf(th), cs = cosf(th);

    #pragma unroll
    for (int l = 0; l < NLAYER; ++l) {
        const float* rw1 = rot_w1 + l * 3 * NH;
        const float* rb1 = rot_b1 + l * NH;
        const float* rw2 = rot_w2 + l * NH;
        const float* tw1 = trans_w1 + l * 2 * NH;
        const float* tb1 = trans_b1 + l * NH;
        const float* tw2 = trans_w2 + l * NH;
        const float* fw1 = refl_w1 + l * 4 * NH;
        const float* fb1 = refl_b1 + l * NH;
        const float* fw2 = refl_w2 + l * NH;
        float acc = rot_b2[l] + trans_b2[l] + refl_b2[l];
        #pragma unroll 8
        for (int h = 0; h < NH; ++h) {
            float hr = fmaxf(dist * rw1[h] + sn * rw1[NH + h] + cs * rw1[2 * NH + h] + rb1[h], 0.f);
            acc += hr * rw2[h];
            float ht = fmaxf(dx * tw1[h] + dy * tw1[NH + h] + tb1[h], 0.f);
            acc += ht * tw2[h];
            float hf = fmaxf(dx * fw1[h] + dy * fw1[NH + h] - dx * fw1[2 * NH + h] - dy * fw1[3 * NH + h] + fb1[h], 0.f);
            acc += hf * fw2[h];
        }
        table[l * 3969 + idx] = acc;
    }
}

// ---------------------------------------------------------------------------
// Row softmax over NS=1024 (f32 in) -> bf16 out
// ---------------------------------------------------------------------------
__global__ __launch_bounds__(256) void softmax_kernel(
    const float* __restrict__ sc, bf16* __restrict__ P)
{
    const float* p = sc + (long)blockIdx.x * NS;
    const int tid = threadIdx.x;
    float4 v = ((const float4*)p)[tid];
    float m = fmaxf(fmaxf(v.x, v.y), fmaxf(v.z, v.w));
    #pragma unroll
    for (int off = 32; off; off >>= 1) m = fmaxf(m, __shfl_xor(m, off));
    __shared__ float red[4], red2[4];
    int wid = tid >> 6;
    if ((tid & 63) == 0) red[wid] = m;
    __syncthreads();
    m = fmaxf(fmaxf(red[0], red[1]), fmaxf(red[2], red[3]));
    v.x = __expf(v.x - m); v.y = __expf(v.y - m);
    v.z = __expf(v.z - m); v.w = __expf(v.w - m);
    float s = v.x + v.y + v.z + v.w;
    #pragma unroll
    for (int off = 32; off; off >>= 1) s += __shfl_xor(s, off);
    if ((tid & 63) == 0) red2[wid] = s;
    __syncthreads();
    s = red2[0] + red2[1] + red2[2] + red2[3];
    float inv = 1.f / s;
    uint2 o;
    o.x = (unsigned)f2bfu(v.x * inv) | ((unsigned)f2bfu(v.y * inv) << 16);
    o.y = (unsigned)f2bfu(v.z * inv) | ((unsigned)f2bfu(v.w * inv) << 16);
    ((uint2*)(P + (long)blockIdx.x * NS))[tid] = o;
}

// ---------------------------------------------------------------------------
// out = LayerNorm(x (+res)); also writes bf16 copy if outb != null
// ---------------------------------------------------------------------------
__global__ __launch_bounds__(256) void add_ln_kernel(
    const float* __restrict__ x, const float* __restrict__ res,
    const float* __restrict__ g, const float* __restrict__ bt,
    float* __restrict__ out, bf16* __restrict__ outb)
{
    long row = blockIdx.x;
    const int tid = threadIdx.x;
    float2 xv = ((const float2*)(x + row * ND))[tid];
    if (res) {
        float2 rv = ((const float2*)(res + row * ND))[tid];
        xv.x += rv.x; xv.y += rv.y;
    }
    float s = xv.x + xv.y;
    float ss = xv.x * xv.x + xv.y * xv.y;
    #pragma unroll
    for (int off = 32; off; off >>= 1) {
        s += __shfl_xor(s, off);
        ss += __shfl_xor(ss, off);
    }
    __shared__ float rs[4], rss[4];
    int wid = tid >> 6;
    if ((tid & 63) == 0) { rs[wid] = s; rss[wid] = ss; }
    __syncthreads();
    s = rs[0] + rs[1] + rs[2] + rs[3];
    ss = rss[0] + rss[1] + rss[2] + rss[3];
    float mu = s * (1.f / ND);
    float var = ss * (1.f / ND) - mu * mu;
    float inv = rsqrtf(var + EPS_LN);
    float2 gv = ((const float2*)g)[tid];
    float2 bv = ((const float2*)bt)[tid];
    float2 o;
    o.x = (xv.x - mu) * inv * gv.x + bv.x;
    o.y = (xv.y - mu) * inv * gv.y + bv.y;
    ((float2*)(out + row * ND))[tid] = o;
    if (outb)
        ((unsigned int*)(outb + row * ND))[tid] =
            (unsigned)f2bfu(o.x) | ((unsigned)f2bfu(o.y) << 16);
}

// ---------------------------------------------------------------------------
// pooled[b][d] = mean_s x[b][s][d]; 256 thr = 64 d-lanes x 4 s-groups
// grid (ND/64, NB) = (8, 2)
// ---------------------------------------------------------------------------
__global__ __launch_bounds__(256) void pool_kernel(
    const float* __restrict__ x, float* __restrict__ pooled)
{
    const int lane = threadIdx.x & 63, sg = threadIdx.x >> 6;
    const int d = blockIdx.x * 64 + lane;
    const int b = blockIdx.y;
    float s = 0.f;
    for (int i = sg; i < NS; i += 4)
        s += x[((long)b * NS + i) * ND + d];
    __shared__ float red[4][64];
    red[sg][lane] = s;
    __syncthreads();
    if (sg == 0)
        pooled[b * ND + d] =
            (red[0][lane] + red[1][lane] + red[2][lane] + red[3][lane]) * (1.f / NS);
}

// ---------------------------------------------------------------------------
// out[b][c] = pooled[b] . fc_w[:,c] + fc_b[c]; 256 thr = 64 c-lanes x 4 d-grp
// grid (ceil(NC/64), NB) = (16, 2)
// ---------------------------------------------------------------------------
__global__ __launch_bounds__(256) void fc_kernel(
    const float* __restrict__ pooled, const float* __restrict__ w,
    const float* __restrict__ bias, float* __restrict__ out)
{
    const int lane = threadIdx.x & 63, dg = threadIdx.x >> 6;
    const int c = blockIdx.x * 64 + lane;
    const int b = blockIdx.y;
    const bool ok = (c < NC);
    const float* p = pooled + b * ND;
    float acc = 0.f;
    for (int d = dg; d < ND; d += 4)
        acc += p[d] * (ok ? w[(long)d * NC + c] : 0.f);
    __shared__ float red[4][64];
    red[dg][lane] = acc;
    __syncthreads();
    if (dg == 0 && ok)
        out[(long)b * NC + c] =
            red[0][lane] + red[1][lane] + red[2][lane] + red[3][lane] + bias[c];
}

// ---------------------------------------------------------------------------
extern "C" void kernel_launch(void* const* d_in, const int* in_sizes, int n_in,
                              void* d_out, int out_size, void* d_ws, size_t ws_size,
                              hipStream_t stream)
{
    const float* x_in   = (const float*)d_in[0];
    const float* coords = (const float*)d_in[1];
    const float* Wq     = (const float*)d_in[2];
    const float* Wk     = (const float*)d_in[3];
    const float* Wv     = (const float*)d_in[4];
    const float* rot_w1 = (const float*)d_in[5];
    const float* rot_b1 = (const float*)d_in[6];
    const float* rot_w2 = (const float*)d_in[7];
    const float* rot_b2 = (const float*)d_in[8];
    const float* trans_w1 = (const float*)d_in[9];
    const float* trans_b1 = (const float*)d_in[10];
    const float* trans_w2 = (const float*)d_in[11];
    const float* trans_b2 = (const float*)d_in[12];
    const float* refl_w1 = (const float*)d_in[13];
    const float* refl_b1 = (const float*)d_in[14];
    const float* refl_w2 = (const float*)d_in[15];
    const float* refl_b2 = (const float*)d_in[16];
    const float* ln1_g = (const float*)d_in[17];
    const float* ln1_b = (const float*)d_in[18];
    const float* ffn_w1 = (const float*)d_in[19];
    const float* ffn_b1 = (const float*)d_in[20];
    const float* ffn_w2 = (const float*)d_in[21];
    const float* ffn_b2 = (const float*)d_in[22];
    const float* ln2_g = (const float*)d_in[23];
    const float* ln2_b = (const float*)d_in[24];
    const float* lnf_g = (const float*)d_in[25];
    const float* lnf_b = (const float*)d_in[26];
    const float* fc_w = (const float*)d_in[27];
    const float* fc_b = (const float*)d_in[28];
    float* out = (float*)d_out;

    const long XSZ = (long)NB * NS * ND;   // 1M elems
    const long SSZ = (long)NB * NS * NS;   // 2M elems

    char* wp = (char*)d_ws;
    auto alloc = [&](long bytes) -> char* {
        char* p = wp; wp += (bytes + 255) & ~(long)255; return p;
    };
    float* x_cur  = (float*)alloc(XSZ * 4);
    bf16*  xb     = (bf16*)alloc(XSZ * 2);
    bf16*  qkv    = (bf16*)alloc((long)NB * NS * 1536 * 2);
    bf16*  vT     = (bf16*)alloc((long)NB * ND * NS * 2);
    float* sc     = (float*)alloc(SSZ * 4);
    bf16*  pb     = (bf16*)alloc(SSZ * 2);
    float* ao     = (float*)alloc(XSZ * 4);
    bf16*  hfb    = (bf16*)alloc((long)NB * NS * NF * 2);
    bf16*  wqkvT  = (bf16*)alloc((long)NLAYER * 3 * ND * ND * 2);
    bf16*  w1T    = (bf16*)alloc((long)NLAYER * NF * ND * 2);
    bf16*  w2T    = (bf16*)alloc((long)NLAYER * ND * NF * 2);
    float* table  = (float*)alloc((long)NLAYER * 3969 * 4);
    float* pooled = (float*)alloc((long)NB * ND * 4);

    const float inv_scale = 1.0f / sqrtf((float)ND);
    const long QKVLD = 1536;

    // ---- weight transposes (batched over layers via z) ----
    tconv_f32_kernel<<<dim3(16, 16, NLAYER), 256, 0, stream>>>(
        Wq, wqkvT + 0,            ND, ND, (long)ND * ND, (long)3 * ND * ND);
    tconv_f32_kernel<<<dim3(16, 16, NLAYER), 256, 0, stream>>>(
        Wk, wqkvT + (long)ND * ND, ND, ND, (long)ND * ND, (long)3 * ND * ND);
    tconv_f32_kernel<<<dim3(16, 16, NLAYER), 256, 0, stream>>>(
        Wv, wqkvT + (long)2 * ND * ND, ND, ND, (long)ND * ND, (long)3 * ND * ND);
    tconv_f32_kernel<<<dim3(64, 16, NLAYER), 256, 0, stream>>>(
        ffn_w1, w1T, ND, NF, (long)ND * NF, (long)NF * ND);
    tconv_f32_kernel<<<dim3(16, 64, NLAYER), 256, 0, stream>>>(
        ffn_w2, w2T, NF, ND, (long)NF * ND, (long)ND * NF);

    xcopy_kernel<<<dim3((int)(XSZ / 1024)), 256, 0, stream>>>(x_in, x_cur, xb);

    bias_table_kernel<<<dim3(16), 256, 0, stream>>>(
        coords, rot_w1, rot_b1, rot_w2, rot_b2,
        trans_w1, trans_b1, trans_w2, trans_b2,
        refl_w1, refl_b1, refl_w2, refl_b2, table);

    for (int l = 0; l < NLAYER; ++l) {
        // QKV fused: [2048,512] @ [1536,512]^T -> qkv bf16 [2048,1536]
        mfma_gemm<128, 128, true, false, false>
            <<<dim3(1536 / 128, (NB * NS) / 128, 1), 256, 0, stream>>>(
            xb, wqkvT + (long)l * 3 * ND * ND, nullptr, qkv, nullptr,
            ND, ND, ND, QKVLD, 0, 0, 0, 0.f);

        // V^T per batch: [1024,512] -> [512,1024]
        tbf_kernel<<<dim3(ND / 32, NS / 32, NB), 256, 0, stream>>>(
            qkv + 2 * ND, vT, QKVLD, NS, (long)NS * QKVLD, (long)ND * NS);

        // scores = Q K^T * inv_scale + table gather, f32 out
        mfma_gemm<128, 128, false, false, true>
            <<<dim3(NS / 128, NS / 128, NB), 256, 0, stream>>>(
            qkv, qkv + ND, nullptr, sc, table + (long)l * 3969,
            ND, QKVLD, QKVLD, NS, (long)NS * QKVLD, (long)NS * QKVLD,
            (long)NS * NS, inv_scale);

        softmax_kernel<<<dim3(NB * NS), 256, 0, stream>>>(sc, pb);

        // attn_out = P @ V : [1024,1024] @ [512,1024]^T -> f32 [1024,512]
        mfma_gemm<64, 64, false, false, false>
            <<<dim3(ND / 64, NS / 64, NB), 256, 0, stream>>>(
            pb, vT, nullptr, ao, nullptr,
            NS, NS, NS, ND, (long)NS * NS, (long)ND * NS, (long)NS * ND, 0.f);

        add_ln_kernel<<<dim3(NB * NS), 256, 0, stream>>>(
            x_cur, ao, ln1_g + (long)l * ND, ln1_b + (long)l * ND, x_cur, xb);

        // FFN1: [2048,512] @ [2048,512]^T + b, ReLU -> bf16 [2048,2048]
        mfma_gemm<128, 128, true, true, false>
            <<<dim3(NF / 128, (NB * NS) / 128, 1), 256, 0, stream>>>(
            xb, w1T + (long)l * NF * ND, ffn_b1 + (long)l * NF, hfb, nullptr,
            ND, ND, ND, NF, 0, 0, 0, 0.f);

        // FFN2: [2048,2048] @ [512,2048]^T + b -> f32 [2048,512]
        mfma_gemm<64, 64, false, false, false>
            <<<dim3(ND / 64, (NB * NS) / 64, 1), 256, 0, stream>>>(
            hfb, w2T + (long)l * ND * NF, ffn_b2 + (long)l * ND, ao, nullptr,
            NF, NF, NF, ND, 0, 0, 0, 0.f);

        add_ln_kernel<<<dim3(NB * NS), 256, 0, stream>>>(
            x_cur, ao, ln2_g + (long)l * ND, ln2_b + (long)l * ND, x_cur, xb);
    }

    add_ln_kernel<<<dim3(NB * NS), 256, 0, stream>>>(
        x_cur, nullptr, lnf_g, lnf_b, x_cur, nullptr);

    pool_kernel<<<dim3(ND / 64, NB), 256, 0, stream>>>(x_cur, pooled);

    fc_kernel<<<dim3((NC + 63) / 64, NB), 256, 0, stream>>>(pooled, fc_w, fc_b, out);
}

// Round 4
// 388.356 us; speedup vs baseline: 1.2409x; 1.2409x over previous
//
#include <hip/hip_runtime.h>
#include <hip/hip_bf16.h>

using bf16 = __hip_bfloat16;
typedef __attribute__((ext_vector_type(8))) short short8;
typedef __attribute__((ext_vector_type(4))) float f32x4;

constexpr int NLAYER = 2;
constexpr int NB = 2;
constexpr int NS = 1024;
constexpr int ND = 512;
constexpr int NH = 32;
constexpr int NF = 2048;
constexpr int NC = 1000;
constexpr float EPS_LN = 1e-5f;

__device__ inline unsigned short f2bfu(float x) {
    union { bf16 h; unsigned short u; } c;
    c.h = __float2bfloat16(x);
    return c.u;
}

#define GLOAD16(gp, lp) __builtin_amdgcn_global_load_lds( \
    (const __attribute__((address_space(1))) void*)(gp),  \
    (__attribute__((address_space(3))) void*)(lp), 16, 0, 0)

// ---------------------------------------------------------------------------
// bf16 MFMA GEMM, C = A[MxK] * B^T[NxK] (+bias) (+ReLU | scores | V^T-write)
// BM x BN tile, 4 waves (2x2), BK=32, double-buffered LDS, 1 barrier/K-step:
//   stage(next) issued BEFORE compute(cur) so global_load_lds overlaps MFMA.
// ---------------------------------------------------------------------------
template<int BM, int BN, bool OUTBF, bool RELU, bool SCORES, bool VOUT>
__global__ __launch_bounds__(256) void mfma_gemm(
    const bf16* __restrict__ A, const bf16* __restrict__ B,
    const float* __restrict__ bias, void* __restrict__ Cout,
    const float* __restrict__ table, bf16* __restrict__ vT,
    int K, int lda, int ldb, int ldc,
    long sA, long sB, long sC, float alpha)
{
    const int bz = blockIdx.z;
    A += (long)bz * sA;
    B += (long)bz * sB;
    const int bm = blockIdx.y * BM, bn = blockIdx.x * BN;
    __shared__ bf16 As[2][BM * 32], Bs[2][BN * 32];
    const int tid = threadIdx.x, lane = tid & 63, wv = tid >> 6;
    const int wr = (wv >> 1) * (BM / 2), wc = (wv & 1) * (BN / 2);
    constexpr int FM = BM / 32, FN = BN / 32;
    f32x4 acc[FM][FN] = {};
    const int r_a = tid >> 2;           // staging row within 64-row sweep
    const int ko = (tid & 3) * 8;       // staging k offset (elems)

    auto stage = [&](int buf, int k0) {
        #pragma unroll
        for (int c = 0; c < BM / 64; ++c)
            GLOAD16(A + (long)(bm + r_a + c * 64) * lda + k0 + ko,
                    &As[buf][c * 2048 + wv * 512]);
        #pragma unroll
        for (int c = 0; c < BN / 64; ++c)
            GLOAD16(B + (long)(bn + r_a + c * 64) * ldb + k0 + ko,
                    &Bs[buf][c * 2048 + wv * 512]);
    };

    const int nt = K >> 5;
    stage(0, 0);
    __syncthreads();
    for (int t = 0; t < nt; ++t) {
        const int cur = t & 1;
        if (t + 1 < nt) stage(cur ^ 1, (t + 1) << 5);
        const short8* Asv = (const short8*)As[cur];
        const short8* Bsv = (const short8*)Bs[cur];
        short8 af[FM], bfr[FN];
        #pragma unroll
        for (int m = 0; m < FM; ++m)
            af[m] = Asv[(wr + m * 16 + (lane & 15)) * 4 + (lane >> 4)];
        #pragma unroll
        for (int n = 0; n < FN; ++n)
            bfr[n] = Bsv[(wc + n * 16 + (lane & 15)) * 4 + (lane >> 4)];
        #pragma unroll
        for (int m = 0; m < FM; ++m)
            #pragma unroll
            for (int n = 0; n < FN; ++n)
                acc[m][n] = __builtin_amdgcn_mfma_f32_16x16x32_bf16(
                    af[m], bfr[n], acc[m][n], 0, 0, 0);
        __syncthreads();
    }

    const int er = (lane >> 4) * 4, ec = lane & 15;
    #pragma unroll
    for (int m = 0; m < FM; ++m) {
        #pragma unroll
        for (int n = 0; n < FN; ++n) {
            const int row0 = bm + wr + m * 16 + er;
            const int col  = bn + wc + n * 16 + ec;
            const float bv = bias ? bias[col] : 0.f;
            #pragma unroll
            for (int e = 0; e < 4; ++e) {
                const int row = row0 + e;
                float v = acc[m][n][e];
                if (SCORES) {
                    int di = (col >> 5) - (row >> 5) + 31;
                    int dj = (col & 31) - (row & 31) + 31;
                    v = v * alpha + table[di * 63 + dj];
                } else {
                    v += bv;
                    if (RELU) v = fmaxf(v, 0.f);
                }
                if (OUTBF)
                    ((bf16*)Cout)[bz * sC + (long)row * ldc + col] = __float2bfloat16(v);
                else
                    ((float*)Cout)[bz * sC + (long)row * ldc + col] = v;
                if (VOUT && col >= 2 * ND) {
                    // V columns: also write V^T[b][d][s] for the PV GEMM
                    int bb = row >> 10;
                    vT[(long)bb * ND * NS + (long)(col - 2 * ND) * NS + (row & (NS - 1))] =
                        __float2bfloat16(v);
                }
            }
        }
    }
}

// ---------------------------------------------------------------------------
// Merged QKV weight transpose+convert: z in [0,6) -> (layer, which of q/k/v)
// dst[l][w][n][k] = (bf16) W[l][k][n]
// ---------------------------------------------------------------------------
__global__ __launch_bounds__(256) void tconv_qkv_kernel(
    const float* __restrict__ Wq, const float* __restrict__ Wk,
    const float* __restrict__ Wv, bf16* __restrict__ dst)
{
    const int z = blockIdx.z;
    const int l = z / 3, wsel = z % 3;
    const float* src = (wsel == 0 ? Wq : wsel == 1 ? Wk : Wv) + (long)l * ND * ND;
    bf16* d = dst + (long)l * 3 * ND * ND + (long)wsel * ND * ND;
    __shared__ float t[32][33];
    const int c0 = blockIdx.x * 32, r0 = blockIdx.y * 32;
    const int lx = threadIdx.x & 31, ly = threadIdx.x >> 5;
    for (int rr = ly; rr < 32; rr += 8)
        t[rr][lx] = src[(long)(r0 + rr) * ND + c0 + lx];
    __syncthreads();
    for (int cc = ly; cc < 32; cc += 8)
        d[(long)(c0 + cc) * ND + r0 + lx] = __float2bfloat16(t[lx][cc]);
}

// generic transpose + f32->bf16, batched over z (for FFN weights)
__global__ __launch_bounds__(256) void tconv_f32_kernel(
    const float* __restrict__ src, bf16* __restrict__ dst,
    int R, int C, long sS, long sD)
{
    src += (long)blockIdx.z * sS;
    dst += (long)blockIdx.z * sD;
    __shared__ float t[32][33];
    const int c0 = blockIdx.x * 32, r0 = blockIdx.y * 32;
    const int lx = threadIdx.x & 31, ly = threadIdx.x >> 5;
    for (int rr = ly; rr < 32; rr += 8)
        t[rr][lx] = src[(long)(r0 + rr) * C + c0 + lx];
    __syncthreads();
    for (int cc = ly; cc < 32; cc += 8)
        dst[(long)(c0 + cc) * R + r0 + lx] = __float2bfloat16(t[lx][cc]);
}

// x_cur = x_in (f32), xb = bf16(x_in)
__global__ __launch_bounds__(256) void xcopy_kernel(
    const float* __restrict__ xin, float* __restrict__ xc, bf16* __restrict__ xb)
{
    long i = (long)blockIdx.x * 256 + threadIdx.x;
    float4 v = ((const float4*)xin)[i];
    ((float4*)xc)[i] = v;
    uint2 o;
    o.x = (unsigned)f2bfu(v.x) | ((unsigned)f2bfu(v.y) << 16);
    o.y = (unsigned)f2bfu(v.z) | ((unsigned)f2bfu(v.w) << 16);
    ((uint2*)xb)[i] = o;
}

// ---------------------------------------------------------------------------
// Pair-bias table: coords form an exact 32x32 grid -> 63x63 table per layer.
// ---------------------------------------------------------------------------
__global__ __launch_bounds__(256) void bias_table_kernel(
    const float* __restrict__ coords,
    const float* __restrict__ rot_w1, const float* __restrict__ rot_b1,
    const float* __restrict__ rot_w2, const float* __restrict__ rot_b2,
    const float* __restrict__ trans_w1, const float* __restrict__ trans_b1,
    const float* __restrict__ trans_w2, const float* __restrict__ trans_b2,
    const float* __restrict__ refl_w1, const float* __restrict__ refl_b1,
    const float* __restrict__ refl_w2, const float* __restrict__ refl_b2,
    float* __restrict__ table)
{
    int idx = blockIdx.x * 256 + threadIdx.x;
    if (idx >= 63 * 63) return;
    int da = idx / 63 - 31, db = idx % 63 - 31;
    int ai = da < 0 ? -da : 0, bi = db < 0 ? -db : 0;
    int i = ai * 32 + bi, j = (ai + da) * 32 + (bi + db);
    float2 ci = ((const float2*)coords)[i];
    float2 cj = ((const float2*)coords)[j];
    float dx = cj.x - ci.x, dy = cj.y - ci.y;
    float dist = sqrtf(dx * dx + dy * dy + 1e-8f);
    float th = atan2f(dy, dx);
    float sn = sinf(th), cs = cosf(th);

    #pragma unroll
    for (int l = 0; l < NLAYER; ++l) {
        const float* rw1 = rot_w1 + l * 3 * NH;
        const float* rb1 = rot_b1 + l * NH;
        const float* rw2 = rot_w2 + l * NH;
        const float* tw1 = trans_w1 + l * 2 * NH;
        const float* tb1 = trans_b1 + l * NH;
        const float* tw2 = trans_w2 + l * NH;
        const float* fw1 = refl_w1 + l * 4 * NH;
        const float* fb1 = refl_b1 + l * NH;
        const float* fw2 = refl_w2 + l * NH;
        float acc = rot_b2[l] + trans_b2[l] + refl_b2[l];
        #pragma unroll 8
        for (int h = 0; h < NH; ++h) {
            float hr = fmaxf(dist * rw1[h] + sn * rw1[NH + h] + cs * rw1[2 * NH + h] + rb1[h], 0.f);
            acc += hr * rw2[h];
            float ht = fmaxf(dx * tw1[h] + dy * tw1[NH + h] + tb1[h], 0.f);
            acc += ht * tw2[h];
            float hf = fmaxf(dx * fw1[h] + dy * fw1[NH + h] - dx * fw1[2 * NH + h] - dy * fw1[3 * NH + h] + fb1[h], 0.f);
            acc += hf * fw2[h];
        }
        table[l * 3969 + idx] = acc;
    }
}

// init: out[b][c] = fc_b[c]; pooled = 0  (both finished by atomics later)
__global__ __launch_bounds__(256) void init_tail_kernel(
    const float* __restrict__ fc_b, float* __restrict__ out, float* __restrict__ pooled)
{
    int i = blockIdx.x * 256 + threadIdx.x;
    if (i < NB * NC) out[i] = fc_b[i % NC];
    int j = i - NB * NC;
    if (j >= 0 && j < NB * ND) pooled[j] = 0.f;
}

// ---------------------------------------------------------------------------
// Row softmax over NS=1024 (f32 in) -> bf16 out
// ---------------------------------------------------------------------------
__global__ __launch_bounds__(256) void softmax_kernel(
    const float* __restrict__ sc, bf16* __restrict__ P)
{
    const float* p = sc + (long)blockIdx.x * NS;
    const int tid = threadIdx.x;
    float4 v = ((const float4*)p)[tid];
    float m = fmaxf(fmaxf(v.x, v.y), fmaxf(v.z, v.w));
    #pragma unroll
    for (int off = 32; off; off >>= 1) m = fmaxf(m, __shfl_xor(m, off));
    __shared__ float red[4], red2[4];
    int wid = tid >> 6;
    if ((tid & 63) == 0) red[wid] = m;
    __syncthreads();
    m = fmaxf(fmaxf(red[0], red[1]), fmaxf(red[2], red[3]));
    v.x = __expf(v.x - m); v.y = __expf(v.y - m);
    v.z = __expf(v.z - m); v.w = __expf(v.w - m);
    float s = v.x + v.y + v.z + v.w;
    #pragma unroll
    for (int off = 32; off; off >>= 1) s += __shfl_xor(s, off);
    if ((tid & 63) == 0) red2[wid] = s;
    __syncthreads();
    s = red2[0] + red2[1] + red2[2] + red2[3];
    float inv = 1.f / s;
    uint2 o;
    o.x = (unsigned)f2bfu(v.x * inv) | ((unsigned)f2bfu(v.y * inv) << 16);
    o.y = (unsigned)f2bfu(v.z * inv) | ((unsigned)f2bfu(v.w * inv) << 16);
    ((uint2*)(P + (long)blockIdx.x * NS))[tid] = o;
}

// ---------------------------------------------------------------------------
// out = LayerNorm(x (+res)); also writes bf16 copy if outb != null
// ---------------------------------------------------------------------------
__global__ __launch_bounds__(256) void add_ln_kernel(
    const float* __restrict__ x, const float* __restrict__ res,
    const float* __restrict__ g, const float* __restrict__ bt,
    float* __restrict__ out, bf16* __restrict__ outb)
{
    long row = blockIdx.x;
    const int tid = threadIdx.x;
    float2 xv = ((const float2*)(x + row * ND))[tid];
    if (res) {
        float2 rv = ((const float2*)(res + row * ND))[tid];
        xv.x += rv.x; xv.y += rv.y;
    }
    float s = xv.x + xv.y;
    float ss = xv.x * xv.x + xv.y * xv.y;
    #pragma unroll
    for (int off = 32; off; off >>= 1) {
        s += __shfl_xor(s, off);
        ss += __shfl_xor(ss, off);
    }
    __shared__ float rs[4], rss[4];
    int wid = tid >> 6;
    if ((tid & 63) == 0) { rs[wid] = s; rss[wid] = ss; }
    __syncthreads();
    s = rs[0] + rs[1] + rs[2] + rs[3];
    ss = rss[0] + rss[1] + rss[2] + rss[3];
    float mu = s * (1.f / ND);
    float var = ss * (1.f / ND) - mu * mu;
    float inv = rsqrtf(var + EPS_LN);
    float2 gv = ((const float2*)g)[tid];
    float2 bv = ((const float2*)bt)[tid];
    float2 o;
    o.x = (xv.x - mu) * inv * gv.x + bv.x;
    o.y = (xv.y - mu) * inv * gv.y + bv.y;
    ((float2*)(out + row * ND))[tid] = o;
    if (outb)
        ((unsigned int*)(outb + row * ND))[tid] =
            (unsigned)f2bfu(o.x) | ((unsigned)f2bfu(o.y) << 16);
}

// ---------------------------------------------------------------------------
// pooled[b][d] += sum over 16 contiguous rows / NS; grid 128 blocks, atomics.
// Fully-coalesced float4 streaming (2 rows per 256-thread sweep).
// ---------------------------------------------------------------------------
__global__ __launch_bounds__(256) void pool_kernel(
    const float* __restrict__ x, float* __restrict__ pooled)
{
    const int tid = threadIdx.x;
    const long row0 = (long)blockIdx.x * 16;
    const int b = (int)(row0 >> 10);
    float ax = 0.f, ay = 0.f, az = 0.f, aw = 0.f;
    #pragma unroll
    for (int it = 0; it < 8; ++it) {
        long r = row0 + it * 2 + (tid >> 7);
        float4 v = ((const float4*)(x + r * ND))[tid & 127];
        ax += v.x; ay += v.y; az += v.z; aw += v.w;
    }
    __shared__ float red[256][4];
    red[tid][0] = ax; red[tid][1] = ay; red[tid][2] = az; red[tid][3] = aw;
    __syncthreads();
    if (tid < 128) {
        int d = tid * 4;
        atomicAdd(&pooled[b * ND + d + 0], (red[tid][0] + red[tid + 128][0]) * (1.f / NS));
        atomicAdd(&pooled[b * ND + d + 1], (red[tid][1] + red[tid + 128][1]) * (1.f / NS));
        atomicAdd(&pooled[b * ND + d + 2], (red[tid][2] + red[tid + 128][2]) * (1.f / NS));
        atomicAdd(&pooled[b * ND + d + 3], (red[tid][3] + red[tid + 128][3]) * (1.f / NS));
    }
}

// ---------------------------------------------------------------------------
// out[b][c] += partial dot over a 64-wide d-chunk; grid (16, NB, 8), atomics.
// ---------------------------------------------------------------------------
__global__ __launch_bounds__(256) void fc_kernel(
    const float* __restrict__ pooled, const float* __restrict__ w,
    float* __restrict__ out)
{
    const int lane = threadIdx.x & 63, dg = threadIdx.x >> 6;
    const int c = blockIdx.x * 64 + lane;
    const int b = blockIdx.y;
    const int d0 = blockIdx.z * 64 + dg * 16;
    const bool ok = (c < NC);
    const float* p = pooled + b * ND;
    float acc = 0.f;
    #pragma unroll
    for (int d = 0; d < 16; ++d)
        acc += p[d0 + d] * (ok ? w[(long)(d0 + d) * NC + c] : 0.f);
    __shared__ float red[4][64];
    red[dg][lane] = acc;
    __syncthreads();
    if (dg == 0 && ok)
        atomicAdd(&out[(long)b * NC + c],
                  red[0][lane] + red[1][lane] + red[2][lane] + red[3][lane]);
}

// ---------------------------------------------------------------------------
extern "C" void kernel_launch(void* const* d_in, const int* in_sizes, int n_in,
                              void* d_out, int out_size, void* d_ws, size_t ws_size,
                              hipStream_t stream)
{
    const float* x_in   = (const float*)d_in[0];
    const float* coords = (const float*)d_in[1];
    const float* Wq     = (const float*)d_in[2];
    const float* Wk     = (const float*)d_in[3];
    const float* Wv     = (const float*)d_in[4];
    const float* rot_w1 = (const float*)d_in[5];
    const float* rot_b1 = (const float*)d_in[6];
    const float* rot_w2 = (const float*)d_in[7];
    const float* rot_b2 = (const float*)d_in[8];
    const float* trans_w1 = (const float*)d_in[9];
    const float* trans_b1 = (const float*)d_in[10];
    const float* trans_w2 = (const float*)d_in[11];
    const float* trans_b2 = (const float*)d_in[12];
    const float* refl_w1 = (const float*)d_in[13];
    const float* refl_b1 = (const float*)d_in[14];
    const float* refl_w2 = (const float*)d_in[15];
    const float* refl_b2 = (const float*)d_in[16];
    const float* ln1_g = (const float*)d_in[17];
    const float* ln1_b = (const float*)d_in[18];
    const float* ffn_w1 = (const float*)d_in[19];
    const float* ffn_b1 = (const float*)d_in[20];
    const float* ffn_w2 = (const float*)d_in[21];
    const float* ffn_b2 = (const float*)d_in[22];
    const float* ln2_g = (const float*)d_in[23];
    const float* ln2_b = (const float*)d_in[24];
    const float* lnf_g = (const float*)d_in[25];
    const float* lnf_b = (const float*)d_in[26];
    const float* fc_w = (const float*)d_in[27];
    const float* fc_b = (const float*)d_in[28];
    float* out = (float*)d_out;

    const long XSZ = (long)NB * NS * ND;   // 1M elems
    const long SSZ = (long)NB * NS * NS;   // 2M elems

    char* wp = (char*)d_ws;
    auto alloc = [&](long bytes) -> char* {
        char* p = wp; wp += (bytes + 255) & ~(long)255; return p;
    };
    float* x_cur  = (float*)alloc(XSZ * 4);
    bf16*  xb     = (bf16*)alloc(XSZ * 2);
    bf16*  qkv    = (bf16*)alloc((long)NB * NS * 1536 * 2);
    bf16*  vT     = (bf16*)alloc((long)NB * ND * NS * 2);
    float* sc     = (float*)alloc(SSZ * 4);
    bf16*  pb     = (bf16*)alloc(SSZ * 2);
    float* ao     = (float*)alloc(XSZ * 4);
    bf16*  hfb    = (bf16*)alloc((long)NB * NS * NF * 2);
    bf16*  wqkvT  = (bf16*)alloc((long)NLAYER * 3 * ND * ND * 2);
    bf16*  w1T    = (bf16*)alloc((long)NLAYER * NF * ND * 2);
    bf16*  w2T    = (bf16*)alloc((long)NLAYER * ND * NF * 2);
    float* table  = (float*)alloc((long)NLAYER * 3969 * 4);
    float* pooled = (float*)alloc((long)NB * ND * 4);

    const float inv_scale = 1.0f / sqrtf((float)ND);
    const long QKVLD = 1536;

    tconv_qkv_kernel<<<dim3(16, 16, 3 * NLAYER), 256, 0, stream>>>(Wq, Wk, Wv, wqkvT);
    tconv_f32_kernel<<<dim3(64, 16, NLAYER), 256, 0, stream>>>(
        ffn_w1, w1T, ND, NF, (long)ND * NF, (long)NF * ND);
    tconv_f32_kernel<<<dim3(16, 64, NLAYER), 256, 0, stream>>>(
        ffn_w2, w2T, NF, ND, (long)NF * ND, (long)ND * NF);

    xcopy_kernel<<<dim3((int)(XSZ / 1024)), 256, 0, stream>>>(x_in, x_cur, xb);

    bias_table_kernel<<<dim3(16), 256, 0, stream>>>(
        coords, rot_w1, rot_b1, rot_w2, rot_b2,
        trans_w1, trans_b1, trans_w2, trans_b2,
        refl_w1, refl_b1, refl_w2, refl_b2, table);

    init_tail_kernel<<<dim3(12), 256, 0, stream>>>(fc_b, out, pooled);

    for (int l = 0; l < NLAYER; ++l) {
        // QKV fused: [2048,512] @ [1536,512]^T -> qkv bf16; V cols also -> vT
        mfma_gemm<128, 128, true, false, false, true>
            <<<dim3(1536 / 128, (NB * NS) / 128, 1), 256, 0, stream>>>(
            xb, wqkvT + (long)l * 3 * ND * ND, nullptr, qkv, nullptr, vT,
            ND, ND, ND, QKVLD, 0, 0, 0, 0.f);

        // scores = Q K^T * inv_scale + table gather, f32 out
        mfma_gemm<128, 128, false, false, true, false>
            <<<dim3(NS / 128, NS / 128, NB), 256, 0, stream>>>(
            qkv, qkv + ND, nullptr, sc, table + (long)l * 3969, nullptr,
            ND, QKVLD, QKVLD, NS, (long)NS * QKVLD, (long)NS * QKVLD,
            (long)NS * NS, inv_scale);

        softmax_kernel<<<dim3(NB * NS), 256, 0, stream>>>(sc, pb);

        // attn_out = P @ V : [1024,1024] @ [512,1024]^T -> f32 [1024,512]
        mfma_gemm<128, 64, false, false, false, false>
            <<<dim3(ND / 64, NS / 128, NB), 256, 0, stream>>>(
            pb, vT, nullptr, ao, nullptr, nullptr,
            NS, NS, NS, ND, (long)NS * NS, (long)ND * NS, (long)NS * ND, 0.f);

        add_ln_kernel<<<dim3(NB * NS), 256, 0, stream>>>(
            x_cur, ao, ln1_g + (long)l * ND, ln1_b + (long)l * ND, x_cur, xb);

        // FFN1: [2048,512] @ [2048,512]^T + b, ReLU -> bf16 [2048,2048]
        mfma_gemm<128, 128, true, true, false, false>
            <<<dim3(NF / 128, (NB * NS) / 128, 1), 256, 0, stream>>>(
            xb, w1T + (long)l * NF * ND, ffn_b1 + (long)l * NF, hfb, nullptr, nullptr,
            ND, ND, ND, NF, 0, 0, 0, 0.f);

        // FFN2: [2048,2048] @ [512,2048]^T + b -> f32 [2048,512]
        mfma_gemm<128, 64, false, false, false, false>
            <<<dim3(ND / 64, (NB * NS) / 128, 1), 256, 0, stream>>>(
            hfb, w2T + (long)l * ND * NF, ffn_b2 + (long)l * ND, ao, nullptr, nullptr,
            NF, NF, NF, ND, 0, 0, 0, 0.f);

        add_ln_kernel<<<dim3(NB * NS), 256, 0, stream>>>(
            x_cur, ao, ln2_g + (long)l * ND, ln2_b + (long)l * ND, x_cur, xb);
    }

    add_ln_kernel<<<dim3(NB * NS), 256, 0, stream>>>(
        x_cur, nullptr, lnf_g, lnf_b, x_cur, nullptr);

    pool_kernel<<<dim3((NB * NS) / 16), 256, 0, stream>>>(x_cur, pooled);

    fc_kernel<<<dim3((NC + 63) / 64, NB, ND / 64), 256, 0, stream>>>(pooled, fc_w, out);
}

// Round 6
// 384.329 us; speedup vs baseline: 1.2539x; 1.0105x over previous
//
#include <hip/hip_runtime.h>
#include <hip/hip_bf16.h>

using bf16 = __hip_bfloat16;
typedef __attribute__((ext_vector_type(8))) short short8;
typedef __attribute__((ext_vector_type(4))) float f32x4;

constexpr int NLAYER = 2;
constexpr int NB = 2;
constexpr int NS = 1024;
constexpr int ND = 512;
constexpr int NH = 32;
constexpr int NF = 2048;
constexpr int NC = 1000;
constexpr float EPS_LN = 1e-5f;

__device__ inline unsigned short f2bfu(float x) {
    union { bf16 h; unsigned short u; } c;
    c.h = __float2bfloat16(x);
    return c.u;
}

#define GLOAD16(gp, lp) __builtin_amdgcn_global_load_lds( \
    (const __attribute__((address_space(1))) void*)(gp),  \
    (__attribute__((address_space(3))) void*)(lp), 16, 0, 0)

// ---------------------------------------------------------------------------
// bf16 MFMA GEMM, C = A[MxK] * B^T[NxK] (+bias) (+ReLU | scores | V^T-write)
// 512 threads = 8 waves in WR x WC grid; wave tile (BM/WR x BN/WC).
// BK=32, double-buffered LDS, stage(next) issued before compute(cur),
// one barrier per K-step. 2 waves/SIMD at 1 block/CU for latency hiding.
// ---------------------------------------------------------------------------
template<int BM, int BN, int WR, int WC, bool OUTBF, bool RELU, bool SCORES, bool VOUT>
__global__ __launch_bounds__(512) void mfma_gemm(
    const bf16* __restrict__ A, const bf16* __restrict__ B,
    const float* __restrict__ bias, void* __restrict__ Cout,
    const float* __restrict__ table, bf16* __restrict__ vT,
    int K, int lda, int ldb, int ldc,
    long sA, long sB, long sC, float alpha)
{
    const int bz = blockIdx.z;
    A += (long)bz * sA;
    B += (long)bz * sB;
    const int bm = blockIdx.y * BM, bn = blockIdx.x * BN;
    __shared__ bf16 As[2][BM * 32], Bs[2][BN * 32];
    const int tid = threadIdx.x, lane = tid & 63, wv = tid >> 6;
    constexpr int WM = BM / WR, WN = BN / WC;
    constexpr int FM = WM / 16, FN = WN / 16;
    const int wr = (wv / WC) * WM, wc = (wv % WC) * WN;
    f32x4 acc[FM][FN] = {};
    const int ko = (lane & 3) * 8;          // staging k offset (elems)
    constexpr int ACH = BM / 16;            // 1024B wave-chunks in A tile
    constexpr int BCH = BN / 16;
    constexpr int NCH = ACH + BCH;

    auto stage = [&](int buf, int k0) {
        for (int c = wv; c < NCH; c += 8) {
            if (c < ACH) {
                int r = c * 16 + (lane >> 2);
                GLOAD16(A + (long)(bm + r) * lda + k0 + ko, &As[buf][c * 512]);
            } else {
                int cc = c - ACH;
                int r = cc * 16 + (lane >> 2);
                GLOAD16(B + (long)(bn + r) * ldb + k0 + ko, &Bs[buf][cc * 512]);
            }
        }
    };

    const int nt = K >> 5;
    stage(0, 0);
    __syncthreads();
    for (int t = 0; t < nt; ++t) {
        const int cur = t & 1;
        if (t + 1 < nt) stage(cur ^ 1, (t + 1) << 5);
        const short8* Asv = (const short8*)As[cur];
        const short8* Bsv = (const short8*)Bs[cur];
        short8 af[FM], bfr[FN];
        #pragma unroll
        for (int m = 0; m < FM; ++m)
            af[m] = Asv[(wr + m * 16 + (lane & 15)) * 4 + (lane >> 4)];
        #pragma unroll
        for (int n = 0; n < FN; ++n)
            bfr[n] = Bsv[(wc + n * 16 + (lane & 15)) * 4 + (lane >> 4)];
        #pragma unroll
        for (int m = 0; m < FM; ++m)
            #pragma unroll
            for (int n = 0; n < FN; ++n)
                acc[m][n] = __builtin_amdgcn_mfma_f32_16x16x32_bf16(
                    af[m], bfr[n], acc[m][n], 0, 0, 0);
        __syncthreads();
    }

    const int er = (lane >> 4) * 4, ec = lane & 15;
    #pragma unroll
    for (int m = 0; m < FM; ++m) {
        #pragma unroll
        for (int n = 0; n < FN; ++n) {
            const int row0 = bm + wr + m * 16 + er;
            const int col  = bn + wc + n * 16 + ec;
            const float bv = bias ? bias[col] : 0.f;
            #pragma unroll
            for (int e = 0; e < 4; ++e) {
                const int row = row0 + e;
                float v = acc[m][n][e];
                if (SCORES) {
                    int di = (col >> 5) - (row >> 5) + 31;
                    int dj = (col & 31) - (row & 31) + 31;
                    v = v * alpha + table[di * 63 + dj];
                } else {
                    v += bv;
                    if (RELU) v = fmaxf(v, 0.f);
                }
                if (OUTBF)
                    ((bf16*)Cout)[bz * sC + (long)row * ldc + col] = __float2bfloat16(v);
                else
                    ((float*)Cout)[bz * sC + (long)row * ldc + col] = v;
                if (VOUT && col >= 2 * ND) {
                    int bb = row >> 10;
                    vT[(long)bb * ND * NS + (long)(col - 2 * ND) * NS + (row & (NS - 1))] =
                        __float2bfloat16(v);
                }
            }
        }
    }
}

// ---------------------------------------------------------------------------
// Flat weight transpose+convert for all weights: 32x32 tiles.
// slots: [0,1536): qkv  [1536,3584): ffn_w1  [3584,5632): ffn_w2
// ---------------------------------------------------------------------------
__global__ __launch_bounds__(256) void wtrans_kernel(
    const float* __restrict__ Wq, const float* __restrict__ Wk,
    const float* __restrict__ Wv, const float* __restrict__ ffn_w1,
    const float* __restrict__ ffn_w2, bf16* __restrict__ wqkvT,
    bf16* __restrict__ w1T, bf16* __restrict__ w2T)
{
    const int s = blockIdx.x;
    const float* src; bf16* dst; int R, C, r0, c0;
    if (s < 1536) {
        int z = s >> 8, rem = s & 255;
        int l = z / 3, wsel = z % 3;
        src = (wsel == 0 ? Wq : wsel == 1 ? Wk : Wv) + (long)l * ND * ND;
        dst = wqkvT + (long)l * 3 * ND * ND + (long)wsel * ND * ND;
        R = ND; C = ND; c0 = (rem & 15) * 32; r0 = (rem >> 4) * 32;
    } else if (s < 3584) {
        int t = s - 1536, l = t >> 10, rem = t & 1023;
        src = ffn_w1 + (long)l * ND * NF;
        dst = w1T + (long)l * NF * ND;
        R = ND; C = NF; c0 = (rem & 63) * 32; r0 = (rem >> 6) * 32;
    } else {
        int t = s - 3584, l = t >> 10, rem = t & 1023;
        src = ffn_w2 + (long)l * NF * ND;
        dst = w2T + (long)l * ND * NF;
        R = NF; C = ND; c0 = (rem & 15) * 32; r0 = (rem >> 4) * 32;
    }
    __shared__ float t[32][33];
    const int lx = threadIdx.x & 31, ly = threadIdx.x >> 5;
    for (int rr = ly; rr < 32; rr += 8)
        t[rr][lx] = src[(long)(r0 + rr) * C + c0 + lx];
    __syncthreads();
    for (int cc = ly; cc < 32; cc += 8)
        dst[(long)(c0 + cc) * R + r0 + lx] = __float2bfloat16(t[lx][cc]);
}

// ---------------------------------------------------------------------------
// Flat prep: [0,1024): xcopy  [1024,1040): bias table  [1040,1052): init
// ---------------------------------------------------------------------------
__global__ __launch_bounds__(256) void prep_kernel(
    const float* __restrict__ xin, float* __restrict__ xc, bf16* __restrict__ xb,
    const float* __restrict__ coords,
    const float* __restrict__ rot_w1, const float* __restrict__ rot_b1,
    const float* __restrict__ rot_w2, const float* __restrict__ rot_b2,
    const float* __restrict__ trans_w1, const float* __restrict__ trans_b1,
    const float* __restrict__ trans_w2, const float* __restrict__ trans_b2,
    const float* __restrict__ refl_w1, const float* __restrict__ refl_b1,
    const float* __restrict__ refl_w2, const float* __restrict__ refl_b2,
    float* __restrict__ table,
    const float* __restrict__ fc_b, float* __restrict__ out,
    float* __restrict__ pooled)
{
    const int blk = blockIdx.x, tid = threadIdx.x;
    if (blk < 1024) {
        long i = (long)blk * 256 + tid;
        float4 v = ((const float4*)xin)[i];
        ((float4*)xc)[i] = v;
        uint2 o;
        o.x = (unsigned)f2bfu(v.x) | ((unsigned)f2bfu(v.y) << 16);
        o.y = (unsigned)f2bfu(v.z) | ((unsigned)f2bfu(v.w) << 16);
        ((uint2*)xb)[i] = o;
        return;
    }
    if (blk < 1040) {
        int idx = (blk - 1024) * 256 + tid;
        if (idx >= 63 * 63) return;
        int da = idx / 63 - 31, db = idx % 63 - 31;
        int ai = da < 0 ? -da : 0, bi = db < 0 ? -db : 0;
        int i = ai * 32 + bi, j = (ai + da) * 32 + (bi + db);
        float2 ci = ((const float2*)coords)[i];
        float2 cj = ((const float2*)coords)[j];
        float dx = cj.x - ci.x, dy = cj.y - ci.y;
        float dist = sqrtf(dx * dx + dy * dy + 1e-8f);
        float th = atan2f(dy, dx);
        float sn = sinf(th), cs = cosf(th);
        #pragma unroll
        for (int l = 0; l < NLAYER; ++l) {
            const float* rw1 = rot_w1 + l * 3 * NH;
            const float* rb1 = rot_b1 + l * NH;
            const float* rw2 = rot_w2 + l * NH;
            const float* tw1 = trans_w1 + l * 2 * NH;
            const float* tb1 = trans_b1 + l * NH;
            const float* tw2 = trans_w2 + l * NH;
            const float* fw1 = refl_w1 + l * 4 * NH;
            const float* fb1 = refl_b1 + l * NH;
            const float* fw2 = refl_w2 + l * NH;
            float acc = rot_b2[l] + trans_b2[l] + refl_b2[l];
            #pragma unroll 8
            for (int h = 0; h < NH; ++h) {
                float hr = fmaxf(dist * rw1[h] + sn * rw1[NH + h] + cs * rw1[2 * NH + h] + rb1[h], 0.f);
                acc += hr * rw2[h];
                float ht = fmaxf(dx * tw1[h] + dy * tw1[NH + h] + tb1[h], 0.f);
                acc += ht * tw2[h];
                float hf = fmaxf(dx * fw1[h] + dy * fw1[NH + h] - dx * fw1[2 * NH + h] - dy * fw1[3 * NH + h] + fb1[h], 0.f);
                acc += hf * fw2[h];
            }
            table[l * 3969 + idx] = acc;
        }
        return;
    }
    {
        int i = (blk - 1040) * 256 + tid;
        if (i < NB * NC) out[i] = fc_b[i % NC];
        int j = i - NB * NC;
        if (j >= 0 && j < NB * ND) pooled[j] = 0.f;
    }
}

// ---------------------------------------------------------------------------
// Row softmax over NS=1024 (f32 in) -> bf16 out
// ---------------------------------------------------------------------------
__global__ __launch_bounds__(256) void softmax_kernel(
    const float* __restrict__ sc, bf16* __restrict__ P)
{
    const float* p = sc + (long)blockIdx.x * NS;
    const int tid = threadIdx.x;
    float4 v = ((const float4*)p)[tid];
    float m = fmaxf(fmaxf(v.x, v.y), fmaxf(v.z, v.w));
    #pragma unroll
    for (int off = 32; off; off >>= 1) m = fmaxf(m, __shfl_xor(m, off));
    __shared__ float red[4], red2[4];
    int wid = tid >> 6;
    if ((tid & 63) == 0) red[wid] = m;
    __syncthreads();
    m = fmaxf(fmaxf(red[0], red[1]), fmaxf(red[2], red[3]));
    v.x = __expf(v.x - m); v.y = __expf(v.y - m);
    v.z = __expf(v.z - m); v.w = __expf(v.w - m);
    float s = v.x + v.y + v.z + v.w;
    #pragma unroll
    for (int off = 32; off; off >>= 1) s += __shfl_xor(s, off);
    if ((tid & 63) == 0) red2[wid] = s;
    __syncthreads();
    s = red2[0] + red2[1] + red2[2] + red2[3];
    float inv = 1.f / s;
    uint2 o;
    o.x = (unsigned)f2bfu(v.x * inv) | ((unsigned)f2bfu(v.y * inv) << 16);
    o.y = (unsigned)f2bfu(v.z * inv) | ((unsigned)f2bfu(v.w * inv) << 16);
    ((uint2*)(P + (long)blockIdx.x * NS))[tid] = o;
}

// ---------------------------------------------------------------------------
// out = LayerNorm(x (+res)); also writes bf16 copy if outb != null
// ---------------------------------------------------------------------------
__global__ __launch_bounds__(256) void add_ln_kernel(
    const float* __restrict__ x, const float* __restrict__ res,
    const float* __restrict__ g, const float* __restrict__ bt,
    float* __restrict__ out, bf16* __restrict__ outb)
{
    long row = blockIdx.x;
    const int tid = threadIdx.x;
    float2 xv = ((const float2*)(x + row * ND))[tid];
    if (res) {
        float2 rv = ((const float2*)(res + row * ND))[tid];
        xv.x += rv.x; xv.y += rv.y;
    }
    float s = xv.x + xv.y;
    float ss = xv.x * xv.x + xv.y * xv.y;
    #pragma unroll
    for (int off = 32; off; off >>= 1) {
        s += __shfl_xor(s, off);
        ss += __shfl_xor(ss, off);
    }
    __shared__ float rs[4], rss[4];
    int wid = tid >> 6;
    if ((tid & 63) == 0) { rs[wid] = s; rss[wid] = ss; }
    __syncthreads();
    s = rs[0] + rs[1] + rs[2] + rs[3];
    ss = rss[0] + rss[1] + rss[2] + rss[3];
    float mu = s * (1.f / ND);
    float var = ss * (1.f / ND) - mu * mu;
    float inv = rsqrtf(var + EPS_LN);
    float2 gv = ((const float2*)g)[tid];
    float2 bv = ((const float2*)bt)[tid];
    float2 o;
    o.x = (xv.x - mu) * inv * gv.x + bv.x;
    o.y = (xv.y - mu) * inv * gv.y + bv.y;
    ((float2*)(out + row * ND))[tid] = o;
    if (outb)
        ((unsigned int*)(outb + row * ND))[tid] =
            (unsigned)f2bfu(o.x) | ((unsigned)f2bfu(o.y) << 16);
}

// ---------------------------------------------------------------------------
// pooled[b][d] += sum over 16 contiguous rows / NS; 128 blocks, atomics.
// ---------------------------------------------------------------------------
__global__ __launch_bounds__(256) void pool_kernel(
    const float* __restrict__ x, float* __restrict__ pooled)
{
    const int tid = threadIdx.x;
    const long row0 = (long)blockIdx.x * 16;
    const int b = (int)(row0 >> 10);
    float ax = 0.f, ay = 0.f, az = 0.f, aw = 0.f;
    #pragma unroll
    for (int it = 0; it < 8; ++it) {
        long r = row0 + it * 2 + (tid >> 7);
        float4 v = ((const float4*)(x + r * ND))[tid & 127];
        ax += v.x; ay += v.y; az += v.z; aw += v.w;
    }
    __shared__ float red[256][4];
    red[tid][0] = ax; red[tid][1] = ay; red[tid][2] = az; red[tid][3] = aw;
    __syncthreads();
    if (tid < 128) {
        int d = tid * 4;
        atomicAdd(&pooled[b * ND + d + 0], (red[tid][0] + red[tid + 128][0]) * (1.f / NS));
        atomicAdd(&pooled[b * ND + d + 1], (red[tid][1] + red[tid + 128][1]) * (1.f / NS));
        atomicAdd(&pooled[b * ND + d + 2], (red[tid][2] + red[tid + 128][2]) * (1.f / NS));
        atomicAdd(&pooled[b * ND + d + 3], (red[tid][3] + red[tid + 128][3]) * (1.f / NS));
    }
}

// ---------------------------------------------------------------------------
// out[b][c] += partial dot over a 64-wide d-chunk; grid (16, NB, 8), atomics.
// ---------------------------------------------------------------------------
__global__ __launch_bounds__(256) void fc_kernel(
    const float* __restrict__ pooled, const float* __restrict__ w,
    float* __restrict__ out)
{
    const int lane = threadIdx.x & 63, dg = threadIdx.x >> 6;
    const int c = blockIdx.x * 64 + lane;
    const int b = blockIdx.y;
    const int d0 = blockIdx.z * 64 + dg * 16;
    const bool ok = (c < NC);
    const float* p = pooled + b * ND;
    float acc = 0.f;
    #pragma unroll
    for (int d = 0; d < 16; ++d)
        acc += p[d0 + d] * (ok ? w[(long)(d0 + d) * NC + c] : 0.f);
    __shared__ float red[4][64];
    red[dg][lane] = acc;
    __syncthreads();
    if (dg == 0 && ok)
        atomicAdd(&out[(long)b * NC + c],
                  red[0][lane] + red[1][lane] + red[2][lane] + red[3][lane]);
}

// ---------------------------------------------------------------------------
extern "C" void kernel_launch(void* const* d_in, const int* in_sizes, int n_in,
                              void* d_out, int out_size, void* d_ws, size_t ws_size,
                              hipStream_t stream)
{
    const float* x_in   = (const float*)d_in[0];
    const float* coords = (const float*)d_in[1];
    const float* Wq     = (const float*)d_in[2];
    const float* Wk     = (const float*)d_in[3];
    const float* Wv     = (const float*)d_in[4];
    const float* rot_w1 = (const float*)d_in[5];
    const float* rot_b1 = (const float*)d_in[6];
    const float* rot_w2 = (const float*)d_in[7];
    const float* rot_b2 = (const float*)d_in[8];
    const float* trans_w1 = (const float*)d_in[9];
    const float* trans_b1 = (const float*)d_in[10];
    const float* trans_w2 = (const float*)d_in[11];
    const float* trans_b2 = (const float*)d_in[12];
    const float* refl_w1 = (const float*)d_in[13];
    const float* refl_b1 = (const float*)d_in[14];
    const float* refl_w2 = (const float*)d_in[15];
    const float* refl_b2 = (const float*)d_in[16];
    const float* ln1_g = (const float*)d_in[17];
    const float* ln1_b = (const float*)d_in[18];
    const float* ffn_w1 = (const float*)d_in[19];
    const float* ffn_b1 = (const float*)d_in[20];
    const float* ffn_w2 = (const float*)d_in[21];
    const float* ffn_b2 = (const float*)d_in[22];
    const float* ln2_g = (const float*)d_in[23];
    const float* ln2_b = (const float*)d_in[24];
    const float* lnf_g = (const float*)d_in[25];
    const float* lnf_b = (const float*)d_in[26];
    const float* fc_w = (const float*)d_in[27];
    const float* fc_b = (const float*)d_in[28];
    float* out = (float*)d_out;

    const long XSZ = (long)NB * NS * ND;   // 1M elems
    const long SSZ = (long)NB * NS * NS;   // 2M elems

    char* wp = (char*)d_ws;
    auto alloc = [&](long bytes) -> char* {
        char* p = wp; wp += (bytes + 255) & ~(long)255; return p;
    };
    float* x_cur  = (float*)alloc(XSZ * 4);
    bf16*  xb     = (bf16*)alloc(XSZ * 2);
    bf16*  qkv    = (bf16*)alloc((long)NB * NS * 1536 * 2);
    bf16*  vT     = (bf16*)alloc((long)NB * ND * NS * 2);
    float* sc     = (float*)alloc(SSZ * 4);
    bf16*  pb     = (bf16*)alloc(SSZ * 2);
    float* ao     = (float*)alloc(XSZ * 4);
    bf16*  hfb    = (bf16*)alloc((long)NB * NS * NF * 2);
    bf16*  wqkvT  = (bf16*)alloc((long)NLAYER * 3 * ND * ND * 2);
    bf16*  w1T    = (bf16*)alloc((long)NLAYER * NF * ND * 2);
    bf16*  w2T    = (bf16*)alloc((long)NLAYER * ND * NF * 2);
    float* table  = (float*)alloc((long)NLAYER * 3969 * 4);
    float* pooled = (float*)alloc((long)NB * ND * 4);

    const float inv_scale = 1.0f / sqrtf((float)ND);
    const long QKVLD = 1536;

    wtrans_kernel<<<dim3(5632), 256, 0, stream>>>(
        Wq, Wk, Wv, ffn_w1, ffn_w2, wqkvT, w1T, w2T);

    prep_kernel<<<dim3(1052), 256, 0, stream>>>(
        x_in, x_cur, xb, coords,
        rot_w1, rot_b1, rot_w2, rot_b2,
        trans_w1, trans_b1, trans_w2, trans_b2,
        refl_w1, refl_b1, refl_w2, refl_b2, table,
        fc_b, out, pooled);

    for (int l = 0; l < NLAYER; ++l) {
        // QKV fused: [2048,512] @ [1536,512]^T -> qkv bf16; V cols also -> vT
        mfma_gemm<128, 128, 4, 2, true, false, false, true>
            <<<dim3(1536 / 128, (NB * NS) / 128, 1), 512, 0, stream>>>(
            xb, wqkvT + (long)l * 3 * ND * ND, nullptr, qkv, nullptr, vT,
            ND, ND, ND, QKVLD, 0, 0, 0, 0.f);

        // scores = Q K^T * inv_scale + table gather, f32 out
        mfma_gemm<128, 128, 4, 2, false, false, true, false>
            <<<dim3(NS / 128, NS / 128, NB), 512, 0, stream>>>(
            qkv, qkv + ND, nullptr, sc, table + (long)l * 3969, nullptr,
            ND, QKVLD, QKVLD, NS, (long)NS * QKVLD, (long)NS * QKVLD,
            (long)NS * NS, inv_scale);

        softmax_kernel<<<dim3(NB * NS), 256, 0, stream>>>(sc, pb);

        // attn_out = P @ V : [1024,1024] @ [512,1024]^T -> f32 [1024,512]
        mfma_gemm<64, 128, 2, 4, false, false, false, false>
            <<<dim3(ND / 128, NS / 64, NB), 512, 0, stream>>>(
            pb, vT, nullptr, ao, nullptr, nullptr,
            NS, NS, NS, ND, (long)NS * NS, (long)ND * NS, (long)NS * ND, 0.f);

        add_ln_kernel<<<dim3(NB * NS), 256, 0, stream>>>(
            x_cur, ao, ln1_g + (long)l * ND, ln1_b + (long)l * ND, x_cur, xb);

        // FFN1: [2048,512] @ [2048,512]^T + b, ReLU -> bf16 [2048,2048]
        mfma_gemm<128, 128, 4, 2, true, true, false, false>
            <<<dim3(NF / 128, (NB * NS) / 128, 1), 512, 0, stream>>>(
            xb, w1T + (long)l * NF * ND, ffn_b1 + (long)l * NF, hfb, nullptr, nullptr,
            ND, ND, ND, NF, 0, 0, 0, 0.f);

        // FFN2: [2048,2048] @ [512,2048]^T + b -> f32 [2048,512]
        mfma_gemm<64, 128, 2, 4, false, false, false, false>
            <<<dim3(ND / 128, (NB * NS) / 64, 1), 512, 0, stream>>>(
            hfb, w2T + (long)l * ND * NF, ffn_b2 + (long)l * ND, ao, nullptr, nullptr,
            NF, NF, NF, ND, 0, 0, 0, 0.f);

        add_ln_kernel<<<dim3(NB * NS), 256, 0, stream>>>(
            x_cur, ao, ln2_g + (long)l * ND, ln2_b + (long)l * ND, x_cur, xb);
    }

    add_ln_kernel<<<dim3(NB * NS), 256, 0, stream>>>(
        x_cur, nullptr, lnf_g, lnf_b, x_cur, nullptr);

    pool_kernel<<<dim3((NB * NS) / 16), 256, 0, stream>>>(x_cur, pooled);

    fc_kernel<<<dim3((NC + 63) / 64, NB, ND / 64), 256, 0, stream>>>(pooled, fc_w, out);
}